// Round 2
// baseline (238.563 us; speedup 1.0000x reference)
//
#include <hip/hip_runtime.h>
#include <stdint.h>

typedef unsigned short u16;
typedef unsigned int u32;
typedef short s16x8 __attribute__((ext_vector_type(8)));
typedef float f32x4 __attribute__((ext_vector_type(4)));

#define LOG2E 1.44269504088896340736f
#define PSTRIDE 72   // ushort elems per P row: 64 data + 8 pad, keeps 16B alignment

__device__ __forceinline__ u16 f2bf(float f) {
    union { float f; u32 i; } c; c.f = f;
    u32 u = c.i + 0x7FFFu + ((c.i >> 16) & 1u);   // RNE
    return (u16)(u >> 16);
}
__device__ __forceinline__ float fast_exp2(float x) {
#if __has_builtin(__builtin_amdgcn_exp2f)
    return __builtin_amdgcn_exp2f(x);
#else
    return exp2f(x);
#endif
}

// ---------------------------------------------------------------------------
// Stage 0: one-shot fp32 -> bf16 conversion of the projection weights into ws.
// Layout in ws (u16 elems): [0,65536) wv | [65536,73728) wq | [73728,81920) wk
// ---------------------------------------------------------------------------
__global__ __launch_bounds__(256) void convert_w(
    const float* __restrict__ wq, const float* __restrict__ wk,
    const float* __restrict__ wv, u16* __restrict__ wsb)
{
    int i = blockIdx.x * 256 + threadIdx.x;   // 0..81919
    float v;
    if (i < 65536)      v = wv[i];
    else if (i < 73728) v = wq[i - 65536];
    else                v = wk[i - 73728];
    wsb[i] = f2bf(v);
}

// ---------------------------------------------------------------------------
// Stage 1: q/k/v projections. Inputs fp32; weights pre-converted bf16.
// Block: one (batch, 64-wide n tile). 256 threads / 4 waves.
// LDS holds x^T [64 n][264 c] bf16 (pad 8). Wave w computes:
//   v^T rows o in [64w, 64w+64): D = wv(A) x x^T(B, LDS) -> v_ws [o][n]
//   q or k cols: wave0/1 -> q cols 0-15/16-31, wave2/3 -> k. D = x^T(A) x w^T(B)
// q is scaled by log2(e) so attention softmax uses exp2.
// ---------------------------------------------------------------------------
__global__ __launch_bounds__(256, 2) void proj_kernel(
    const float* __restrict__ x,
    const u16* __restrict__ wq_bf, const float* __restrict__ bq,
    const u16* __restrict__ wk_bf, const float* __restrict__ bk,
    const u16* __restrict__ wv_bf, const float* __restrict__ bv,
    u16* __restrict__ q_ws, u16* __restrict__ k_ws, u16* __restrict__ v_ws)
{
    __shared__ u16 XT[64 * 264];
    const int t  = threadIdx.x;
    const int b  = blockIdx.x >> 6;
    const int n0 = (blockIdx.x & 63) << 6;

    // --- stage x^T into LDS: fp32 loads, RNE to bf16, pack c/c+1 pairs ---
    {
        const int m  = t & 15;   // c-pair selector
        const int ng = t >> 4;   // n-group of 4
        u32* lds32 = (u32*)XT;
        for (int s = 0; s < 8; ++s) {
            int c = s * 32 + m * 2;
            size_t base = (size_t)(b * 256 + c) * 4096 + n0 + ng * 4;
            float4 r0 = *(const float4*)(x + base);          // row c,   n..n+3
            float4 r1 = *(const float4*)(x + base + 4096);   // row c+1, n..n+3
            int rowb = ng * 4, cw = c >> 1;
            lds32[(rowb + 0) * 132 + cw] = (u32)f2bf(r0.x) | ((u32)f2bf(r1.x) << 16);
            lds32[(rowb + 1) * 132 + cw] = (u32)f2bf(r0.y) | ((u32)f2bf(r1.y) << 16);
            lds32[(rowb + 2) * 132 + cw] = (u32)f2bf(r0.z) | ((u32)f2bf(r1.z) << 16);
            lds32[(rowb + 3) * 132 + cw] = (u32)f2bf(r0.w) | ((u32)f2bf(r1.w) << 16);
        }
    }
    __syncthreads();

    const int wave = t >> 6, lane = t & 63, quad = lane >> 4, l15 = lane & 15;

    f32x4 accV[4][4];
    f32x4 accQK[4];
    for (int i = 0; i < 4; ++i) {
        accQK[i] = (f32x4)0.0f;
        for (int j = 0; j < 4; ++j) accV[i][j] = (f32x4)0.0f;
    }

    const u16* wsel = (wave < 2) ? wq_bf : wk_bf;
    const int qc = ((wave & 1) << 4) + l15;

    for (int co = 0; co < 8; ++co) {
        int cb = co * 32 + quad * 8;
        s16x8 X[4], WV[4], WQK;
        for (int ct = 0; ct < 4; ++ct)
            X[ct] = *(const s16x8*)(XT + (ct * 16 + l15) * 264 + cb);
        for (int rt = 0; rt < 4; ++rt)
            WV[rt] = *(const s16x8*)(wv_bf + (size_t)(wave * 64 + rt * 16 + l15) * 256 + cb);
        WQK = *(const s16x8*)(wsel + (size_t)qc * 256 + cb);

        for (int rt = 0; rt < 4; ++rt)
            for (int ct = 0; ct < 4; ++ct)
                accV[rt][ct] = __builtin_amdgcn_mfma_f32_16x16x32_bf16(WV[rt], X[ct], accV[rt][ct], 0, 0, 0);
        for (int r = 0; r < 4; ++r)
            accQK[r] = __builtin_amdgcn_mfma_f32_16x16x32_bf16(X[r], WQK, accQK[r], 0, 0, 0);
    }

    // v epilogue: D rows = o, cols = n  ->  v_ws[(b,o),n]  (bf16)
    for (int rt = 0; rt < 4; ++rt) {
        int ob = wave * 64 + rt * 16 + quad * 4;
        float bvf[4];
        for (int r = 0; r < 4; ++r) bvf[r] = bv[ob + r];
        for (int ct = 0; ct < 4; ++ct) {
            int n = n0 + ct * 16 + l15;
            for (int r = 0; r < 4; ++r)
                v_ws[(size_t)(b * 256 + ob + r) * 4096 + n] = f2bf(accV[rt][ct][r] + bvf[r]);
        }
    }
    // q/k epilogue: D rows = n, cols = qc -> {q,k}_ws[(b,n),qc]  (bf16)
    {
        float bias  = (wave < 2 ? bq : bk)[qc];
        float scale = (wave < 2) ? LOG2E : 1.0f;
        u16* dst = (wave < 2) ? q_ws : k_ws;
        for (int r = 0; r < 4; ++r)
            for (int reg = 0; reg < 4; ++reg) {
                int n = n0 + r * 16 + quad * 4 + reg;
                dst[(size_t)(b * 4096 + n) * 32 + qc] = f2bf((accQK[r][reg] + bias) * scale);
            }
    }
}

// ---------------------------------------------------------------------------
// Stage 2: flash attention. Block: (batch, 32-row q tile). 4 waves, wave w
// owns o in [64w,64w+64). Each wave redundantly computes S^T = K·Q^T
// (rows m, cols n), online softmax along m (per-lane folds + 2 shuffles),
// P^T packed to private LDS, PV via O^T[o][n] += V(A)·P^T(B). No barriers.
// Residual x and out are fp32.
// ---------------------------------------------------------------------------
__global__ __launch_bounds__(256, 2) void attn_kernel(
    const u16* __restrict__ q_ws, const u16* __restrict__ k_ws, const u16* __restrict__ v_ws,
    const float* __restrict__ x, const float* __restrict__ gamma_p, float* __restrict__ out)
{
    __shared__ u16 P[4][32 * PSTRIDE];
    const int t  = threadIdx.x;
    const int b  = blockIdx.x >> 7;
    const int n0 = (blockIdx.x & 127) << 5;
    const int wave = t >> 6, lane = t & 63, quad = lane >> 4, l15 = lane & 15;
    const int obase = wave << 6;
    u16* Pw = P[wave];

    s16x8 QF[2];
    for (int ct = 0; ct < 2; ++ct)
        QF[ct] = *(const s16x8*)(q_ws + (size_t)(b * 4096 + n0 + ct * 16 + l15) * 32 + quad * 8);

    f32x4 accO[4][2];
    for (int i = 0; i < 4; ++i) for (int j = 0; j < 2; ++j) accO[i][j] = (f32x4)0.0f;
    float m_run[2] = { -1e30f, -1e30f };
    float l_run[2] = { 0.0f, 0.0f };

    for (int mt = 0; mt < 64; ++mt) {
        const int m0 = mt << 6;

        s16x8 KF[4];
        for (int rt = 0; rt < 4; ++rt)
            KF[rt] = *(const s16x8*)(k_ws + (size_t)(b * 4096 + m0 + rt * 16 + l15) * 32 + quad * 8);

        f32x4 ST[4][2];
        for (int rt = 0; rt < 4; ++rt)
            for (int ct = 0; ct < 2; ++ct) {
                f32x4 z = (f32x4)0.0f;
                ST[rt][ct] = __builtin_amdgcn_mfma_f32_16x16x32_bf16(KF[rt], QF[ct], z, 0, 0, 0);
            }

        float alpha[2];
        for (int ct = 0; ct < 2; ++ct) {
            // tile max along m (this lane's 16 m's, then across quads)
            float tm = -1e30f;
            for (int rt = 0; rt < 4; ++rt)
                for (int r = 0; r < 4; ++r) tm = fmaxf(tm, ST[rt][ct][r]);
            tm = fmaxf(tm, __shfl_xor(tm, 16, 64));
            tm = fmaxf(tm, __shfl_xor(tm, 32, 64));
            float mn = fmaxf(m_run[ct], tm);
            alpha[ct] = fast_exp2(m_run[ct] - mn);
            m_run[ct] = mn;

            float s = 0.0f;
            for (int rt = 0; rt < 4; ++rt) {
                float p0 = fast_exp2(ST[rt][ct][0] - mn);
                float p1 = fast_exp2(ST[rt][ct][1] - mn);
                float p2 = fast_exp2(ST[rt][ct][2] - mn);
                float p3 = fast_exp2(ST[rt][ct][3] - mn);
                s += (p0 + p1) + (p2 + p3);
                uint2 pk;
                pk.x = (u32)f2bf(p0) | ((u32)f2bf(p1) << 16);
                pk.y = (u32)f2bf(p2) | ((u32)f2bf(p3) << 16);
                // P^T LDS: [n=ct*16+l15][m=rt*16+quad*4 .. +3]
                *(uint2*)(Pw + (ct * 16 + l15) * PSTRIDE + rt * 16 + quad * 4) = pk;
            }
            s += __shfl_xor(s, 16, 64);
            s += __shfl_xor(s, 32, 64);
            l_run[ct] = l_run[ct] * alpha[ct] + s;
            for (int rt = 0; rt < 4; ++rt)
                for (int r = 0; r < 4; ++r) accO[rt][ct][r] *= alpha[ct];
        }

        // PV: O^T[o][n] += V[o][m] * P^T[m][n]
        for (int kt = 0; kt < 2; ++kt) {
            s16x8 PF[2];
            for (int ct = 0; ct < 2; ++ct)
                PF[ct] = *(const s16x8*)(Pw + (ct * 16 + l15) * PSTRIDE + kt * 32 + quad * 8);
            for (int rt = 0; rt < 4; ++rt) {
                s16x8 VF = *(const s16x8*)(v_ws + (size_t)(b * 256 + obase + rt * 16 + l15) * 4096
                                           + m0 + kt * 32 + quad * 8);
                for (int ct = 0; ct < 2; ++ct)
                    accO[rt][ct] = __builtin_amdgcn_mfma_f32_16x16x32_bf16(VF, PF[ct], accO[rt][ct], 0, 0, 0);
            }
        }
    }

    // epilogue: out = gamma * O/l + x   (fp32 in/out)
    const float gamma = gamma_p[0];
    for (int ct = 0; ct < 2; ++ct) {
        float rinv = gamma / l_run[ct];
        int n = n0 + ct * 16 + l15;
        for (int rt = 0; rt < 4; ++rt) {
            int ob = obase + rt * 16 + quad * 4;
            for (int r = 0; r < 4; ++r) {
                size_t idx = (size_t)(b * 256 + ob + r) * 4096 + n;
                out[idx] = accO[rt][ct][r] * rinv + x[idx];
            }
        }
    }
}

extern "C" void kernel_launch(void* const* d_in, const int* in_sizes, int n_in,
                              void* d_out, int out_size, void* d_ws, size_t ws_size,
                              hipStream_t stream) {
    const float* x  = (const float*)d_in[0];
    const float* wq = (const float*)d_in[1];
    const float* bq = (const float*)d_in[2];
    const float* wk = (const float*)d_in[3];
    const float* bk = (const float*)d_in[4];
    const float* wv = (const float*)d_in[5];
    const float* bv = (const float*)d_in[6];
    const float* gm = (const float*)d_in[7];

    u16* wsb   = (u16*)d_ws;
    u16* wv_bf = wsb;                       // [256,256] bf16
    u16* wq_bf = wsb + 65536;               // [32,256]  bf16
    u16* wk_bf = wsb + 73728;               // [32,256]  bf16
    u16* q_ws  = wsb + 81920;               // [4,4096,32] bf16, q pre-scaled by log2e
    u16* k_ws  = q_ws + 4 * 4096 * 32;      // [4,4096,32] bf16
    u16* v_ws  = k_ws + 4 * 4096 * 32;      // [4,256,4096] bf16

    convert_w<<<320, 256, 0, stream>>>(wq, wk, wv, wsb);
    proj_kernel<<<256, 256, 0, stream>>>(x, wq_bf, bq, wk_bf, bk, wv_bf, bv, q_ws, k_ws, v_ws);
    attn_kernel<<<512, 256, 0, stream>>>(q_ws, k_ws, v_ws, x, gm, (float*)d_out);
}